// Round 11
// baseline (178.631 us; speedup 1.0000x reference)
//
#include <hip/hip_runtime.h>

#define B_LEN 32
#define C_LEN 512
#define L_LEN 4096
#define H_LEN 8
#define WIN 9

typedef __attribute__((ext_vector_type(8))) short short8v;  // 8 bf16 = 16B
typedef __attribute__((ext_vector_type(4))) float float4v;

// fp32 -> bf16 RNE
__device__ __forceinline__ short f2bf(float f) {
  unsigned u = __float_as_uint(f);
  unsigned r = (u + 0x7fffu + ((u >> 16) & 1u)) >> 16;
  return (short)r;
}

// ------------- Kernel 0: repack W [H][C][9] -> Wt bf16 [9][16][512] ----------
// h rows 8..15 are ZERO so MFMA A-rows 8-15 produce zeros.
__global__ __launch_bounds__(256) void repack_w_bf16(
    const float* __restrict__ W, short* __restrict__ Wt)
{
  const int i = blockIdx.x * 256 + threadIdx.x; // over 9*16*512
  if (i >= WIN * 16 * C_LEN) return;
  const int c = i & 511;
  const int h = (i >> 9) & 15;
  const int w = i / (16 * C_LEN);
  const float v = (h < H_LEN) ? W[((size_t)h * C_LEN + c) * WIN + w] : 0.f;
  Wt[i] = f2bf(v);
}

// ------------- Kernel 1: conv via bf16 MFMA, wave-autonomous pipeline --------
// grid (16 lt, 32 b) = 512 blocks (3/CU), block 256 (4 waves). Each wave owns
// 64 l; stages its OWN [72 l][32 c] bf16 double-buffered slice. Per chunk:
//   WLOAD (9 W-frag loads FIRST -> compute's W-wait is vmcnt(9), ~200cyc once)
//   LOADK (next chunk's 9 x float4 -> drained only at WRITEB, after compute)
//   COMPUTE (36 ds_read_b128 + 36 MFMA, pure LDS)
//   WRITEB (vmcnt for x, cvt, swizzled ds_write)
// Waves walk chunks in staggered order ((i + 4*wid) & 15) so their load
// bursts/stalls interleave instead of aligning. All values in NAMED regs.
#define SLICE 5760 // 72 rows * 80 B

__global__ __launch_bounds__(256, 3) void conv_mfma(
    const float* __restrict__ x, const short* __restrict__ Wt,
    float* __restrict__ part)
{
  __shared__ short xt[4 * 2 * (SLICE / 2)]; // 46080 B
  const int t = threadIdx.x;
  const int lane = t & 63;
  const int wid = t >> 6;
  const int j15 = lane & 15;
  const int g = lane >> 4;
  const int g16 = g * 16;
  const int b = blockIdx.y;
  const int l0b = blockIdx.x * 256;
  const int wl0 = wid * 64;
  const int s = l0b + wl0 - 4; // slice row r <-> x[s + r]
  const float* xb = x + (size_t)b * C_LEN * L_LEN;

  char* bufA = (char*)&xt[0] + (size_t)wid * 2 * SLICE;
  char* bufB = bufA + SLICE;

  // staging lane roles
  const int q = lane & 15;      // l-quad (bulk rows 4+4q .. 7+4q)
  const int chigh = lane >> 4;  // c-octet 0..3
  const int bl = s + 4 + 4 * q; // bulk l (always in bounds)
  const int hside = lane >> 5;  // 0: rows 0-3, 1: rows 68-71
  const int hc = lane & 31;     // halo channel within chunk
  const int hl = s + (hside ? 68 : 0);
  const bool hok = (hl >= 0) && (hl + 3 < L_LEN);
  const int hlc = hok ? hl : (hside ? (L_LEN - 4) : 0); // safe clamped addr
  const int hr = hside ? 68 : 0;
  const int hkey = hside ? 16 : 0; // ((68>>2)&3)<<4 = 16; rows 0-3 -> 0

  float4 L0, L1, L2, L3, L4, L5, L6, L7, LH;
  short8v wn0, wn1, wn2, wn3, wn4, wn5, wn6, wn7, wn8;
  const float4 z4 = make_float4(0.f, 0.f, 0.f, 0.f);

#define WLOAD(K)                                                               \
  {                                                                            \
    const short* Wb = Wt + (K) * 32 + j15 * 512 + 8 * g;                       \
    wn0 = *(const short8v*)(Wb);                                               \
    wn1 = *(const short8v*)(Wb + 1 * 8192);                                    \
    wn2 = *(const short8v*)(Wb + 2 * 8192);                                    \
    wn3 = *(const short8v*)(Wb + 3 * 8192);                                    \
    wn4 = *(const short8v*)(Wb + 4 * 8192);                                    \
    wn5 = *(const short8v*)(Wb + 5 * 8192);                                    \
    wn6 = *(const short8v*)(Wb + 6 * 8192);                                    \
    wn7 = *(const short8v*)(Wb + 7 * 8192);                                    \
    wn8 = *(const short8v*)(Wb + 8 * 8192);                                    \
  }

#define LOADK(K)                                                               \
  {                                                                            \
    const float* bsrc = xb + (size_t)((K) * 32 + chigh * 8) * L_LEN + bl;      \
    L0 = *(const float4*)(bsrc);                                               \
    L1 = *(const float4*)(bsrc + 1 * (size_t)L_LEN);                           \
    L2 = *(const float4*)(bsrc + 2 * (size_t)L_LEN);                           \
    L3 = *(const float4*)(bsrc + 3 * (size_t)L_LEN);                           \
    L4 = *(const float4*)(bsrc + 4 * (size_t)L_LEN);                           \
    L5 = *(const float4*)(bsrc + 5 * (size_t)L_LEN);                           \
    L6 = *(const float4*)(bsrc + 6 * (size_t)L_LEN);                           \
    L7 = *(const float4*)(bsrc + 7 * (size_t)L_LEN);                           \
    LH = *(const float4*)(xb + (size_t)((K) * 32 + hc) * L_LEN + hlc);         \
    if (!hok) LH = z4;                                                         \
  }

#define WROW(BB, E, CMP)                                                       \
  {                                                                            \
    const int r = 4 + 4 * q + (E);                                             \
    short8v v = { f2bf(L0.CMP), f2bf(L1.CMP), f2bf(L2.CMP), f2bf(L3.CMP),      \
                  f2bf(L4.CMP), f2bf(L5.CMP), f2bf(L6.CMP), f2bf(L7.CMP) };    \
    *(short8v*)((BB) + r * 80 + ((chigh * 16) ^ (((r >> 2) & 3) << 4))) = v;   \
  }

#define WRITEB(BB)                                                             \
  {                                                                            \
    WROW(BB, 0, x) WROW(BB, 1, y) WROW(BB, 2, z) WROW(BB, 3, w)                \
    *(short*)((BB) + (hr + 0) * 80 + ((hc * 2) ^ hkey)) = f2bf(LH.x);          \
    *(short*)((BB) + (hr + 1) * 80 + ((hc * 2) ^ hkey)) = f2bf(LH.y);          \
    *(short*)((BB) + (hr + 2) * 80 + ((hc * 2) ^ hkey)) = f2bf(LH.z);          \
    *(short*)((BB) + (hr + 3) * 80 + ((hc * 2) ^ hkey)) = f2bf(LH.w);          \
  }

#define MSTEP(BB, ROFF, ACC, WF)                                               \
  {                                                                            \
    const int r = rw + (ROFF);                                                 \
    short8v xf = *(const short8v*)((BB) + r * 80 + (g16 ^ (((r >> 2) & 3) << 4))); \
    ACC = __builtin_amdgcn_mfma_f32_16x16x32_bf16(WF, xf, ACC, 0, 0, 0);       \
  }

#define CSTEP(BB, W, WF)                                                       \
  {                                                                            \
    const int rw = j15 + (W);                                                  \
    MSTEP(BB, 0, acc0, WF) MSTEP(BB, 16, acc1, WF)                             \
    MSTEP(BB, 32, acc2, WF) MSTEP(BB, 48, acc3, WF)                            \
  }

#define COMPUTE(BB)                                                            \
  {                                                                            \
    CSTEP(BB, 0, wn0) CSTEP(BB, 1, wn1) CSTEP(BB, 2, wn2)                      \
    CSTEP(BB, 3, wn3) CSTEP(BB, 4, wn4) CSTEP(BB, 5, wn5)                      \
    CSTEP(BB, 6, wn6) CSTEP(BB, 7, wn7) CSTEP(BB, 8, wn8)                      \
  }

  float4v acc0 = {0.f, 0.f, 0.f, 0.f};
  float4v acc1 = acc0, acc2 = acc0, acc3 = acc0;

  const int st = wid * 4; // per-wave chunk-order stagger
#define CK(I) (((I) + st) & 15)

  // prologue: stage chunk CK(0) into bufA
  LOADK(CK(0))
  WRITEB(bufA)

  for (int i = 0; i < 16; i += 2) {
    // phase A: compute CK(i) from bufA; prefetch x of CK(i+1)
    WLOAD(CK(i))          // W first: compute waits vmcnt(9), x stays in flight
    LOADK(CK(i + 1))
    COMPUTE(bufA)
    WRITEB(bufB)
    // phase B: compute CK(i+1) from bufB; prefetch x of CK(i+2)
    WLOAD(CK(i + 1))
    if (i + 2 < 16) { LOADK(CK(i + 2)) }
    COMPUTE(bufB)
    if (i + 2 < 16) { WRITEB(bufA) }
  }

  // D: col = lane&15 = l-offset, row = (lane>>4)*4 + reg = h (valid g<2)
  if (lane < 32) {
    float* d = part + ((size_t)b * H_LEN + 4 * g) * L_LEN + (l0b + wl0 + j15);
#pragma unroll
    for (int r = 0; r < 4; ++r) {
      d[(size_t)r * L_LEN +  0] = acc0[r];
      d[(size_t)r * L_LEN + 16] = acc1[r];
      d[(size_t)r * L_LEN + 32] = acc2[r];
      d[(size_t)r * L_LEN + 48] = acc3[r];
    }
  }
#undef WLOAD
#undef LOADK
#undef WROW
#undef WRITEB
#undef MSTEP
#undef CSTEP
#undef COMPUTE
#undef CK
}

// ------------- Kernel 2: softmax over L --------------------------------------
__global__ __launch_bounds__(256) void softmax_rows(
    const float* __restrict__ part, float* __restrict__ focus)
{
  __shared__ float red[256];
  const int r = blockIdx.x; // b*H + h
  const int t = threadIdx.x;
  float v[16];
#pragma unroll
  for (int k = 0; k < 4; ++k) {
    const int i4 = (t + 256 * k) * 4;
    float4 a = *reinterpret_cast<const float4*>(&part[(size_t)r * L_LEN + i4]);
    v[4 * k + 0] = a.x; v[4 * k + 1] = a.y; v[4 * k + 2] = a.z; v[4 * k + 3] = a.w;
  }
  // bias b[h] is constant along L -> softmax-invariant -> skipped
  float m = v[0];
#pragma unroll
  for (int k = 1; k < 16; ++k) m = fmaxf(m, v[k]);
  red[t] = m;
  __syncthreads();
  for (int s = 128; s > 0; s >>= 1) {
    if (t < s) red[t] = fmaxf(red[t], red[t + s]);
    __syncthreads();
  }
  m = red[0];
  __syncthreads();
  float sum = 0.f;
#pragma unroll
  for (int k = 0; k < 16; ++k) { v[k] = __expf(v[k] - m); sum += v[k]; }
  red[t] = sum;
  __syncthreads();
  for (int s = 128; s > 0; s >>= 1) {
    if (t < s) red[t] += red[t + s];
    __syncthreads();
  }
  const float inv = 1.f / red[0];
#pragma unroll
  for (int k = 0; k < 4; ++k) {
    const int i4 = (t + 256 * k) * 4;
    float4 a;
    a.x = v[4 * k + 0] * inv; a.y = v[4 * k + 1] * inv;
    a.z = v[4 * k + 2] * inv; a.w = v[4 * k + 3] * inv;
    *reinterpret_cast<float4*>(&focus[(size_t)r * L_LEN + i4]) = a;
  }
}

// ------------- Kernel 3a: partial pooled over an L-split ---------------------
#define K3_ST 68
#define K3_NS 4

__global__ __launch_bounds__(256) void pool_partial(
    const float* __restrict__ x, const float* __restrict__ focus,
    float* __restrict__ pool2)
{
  __shared__ float xs[64 * K3_ST];
  const int t = threadIdx.x;
  const int cl = t & 63;
  const int p = t >> 6;
  const int pu = __builtin_amdgcn_readfirstlane(p);
  const int b = blockIdx.y;
  const int c0 = blockIdx.x * 64;
  const int lbeg = blockIdx.z * (L_LEN / K3_NS);
  const float* f0 = focus + ((size_t)b * H_LEN + pu) * L_LEN;
  const float* f1 = f0 + 4 * (size_t)L_LEN;
  const float* xb = x + (size_t)b * C_LEN * L_LEN;
  const int srow = t >> 4;
  const int scol = (t & 15) * 4;
  float acc0 = 0.f, acc1 = 0.f;

  for (int l0 = lbeg; l0 < lbeg + L_LEN / K3_NS; l0 += 64) {
    __syncthreads();
#pragma unroll
    for (int pass = 0; pass < 4; ++pass) {
      const int c = srow + pass * 16;
      float4 v = *reinterpret_cast<const float4*>(&xb[(size_t)(c0 + c) * L_LEN + l0 + scol]);
      *reinterpret_cast<float4*>(&xs[c * K3_ST + scol]) = v;
    }
    __syncthreads();
#pragma unroll
    for (int l4 = 0; l4 < 16; ++l4) {
      const float4 xv = *reinterpret_cast<const float4*>(&xs[cl * K3_ST + 4 * l4]);
      const int li = l0 + 4 * l4;
      acc0 = fmaf(xv.x, f0[li + 0], acc0);
      acc0 = fmaf(xv.y, f0[li + 1], acc0);
      acc0 = fmaf(xv.z, f0[li + 2], acc0);
      acc0 = fmaf(xv.w, f0[li + 3], acc0);
      acc1 = fmaf(xv.x, f1[li + 0], acc1);
      acc1 = fmaf(xv.y, f1[li + 1], acc1);
      acc1 = fmaf(xv.z, f1[li + 2], acc1);
      acc1 = fmaf(xv.w, f1[li + 3], acc1);
    }
  }
  float* dst = pool2 + (((size_t)blockIdx.z * B_LEN + b) * C_LEN + c0 + cl) * H_LEN;
  dst[p] = acc0;
  dst[p + 4] = acc1;
}

// ------------- Kernel 3b: sum L-splits, max over heads ------------------------
__global__ __launch_bounds__(256) void pool_reduce(
    const float* __restrict__ pool2, float* __restrict__ out)
{
  const int i = blockIdx.x * 256 + threadIdx.x; // over B*C
  float s[H_LEN];
#pragma unroll
  for (int h = 0; h < H_LEN; ++h) s[h] = 0.f;
  for (int ls = 0; ls < K3_NS; ++ls) {
    const float* src = pool2 + ((size_t)ls * B_LEN * C_LEN + i) * H_LEN;
    float4 a = *reinterpret_cast<const float4*>(src);
    float4 b4 = *reinterpret_cast<const float4*>(src + 4);
    s[0] += a.x; s[1] += a.y; s[2] += a.z; s[3] += a.w;
    s[4] += b4.x; s[5] += b4.y; s[6] += b4.z; s[7] += b4.w;
  }
  float m = s[0];
#pragma unroll
  for (int h = 1; h < H_LEN; ++h) m = fmaxf(m, s[h]);
  out[i] = m;
}

extern "C" void kernel_launch(void* const* d_in, const int* in_sizes, int n_in,
                              void* d_out, int out_size, void* d_ws, size_t ws_size,
                              hipStream_t stream)
{
  const float* x = (const float*)d_in[0];
  const float* W = (const float*)d_in[1];
  // d_in[2] = bias: constant along L, softmax-invariant -> no effect on output.
  float* out = (float*)d_out;
  float* ws = (float*)d_ws;

  const size_t PART = (size_t)B_LEN * H_LEN * L_LEN;            // 1M floats
  const size_t POOL2N = (size_t)K3_NS * B_LEN * C_LEN * H_LEN;  // 512K floats

  float* part = ws;                      // 4 MB
  float* focus = ws + PART;              // 4 MB
  float* pool2 = focus + PART;           // 2 MB
  short* Wt = (short*)(pool2 + POOL2N);  // 147 KB

  hipLaunchKernelGGL(repack_w_bf16, dim3((WIN * 16 * C_LEN + 255) / 256), dim3(256), 0,
                     stream, W, Wt);
  hipLaunchKernelGGL(conv_mfma, dim3(L_LEN / 256, B_LEN), dim3(256), 0,
                     stream, x, Wt, part);
  hipLaunchKernelGGL(softmax_rows, dim3(B_LEN * H_LEN), dim3(256), 0,
                     stream, part, focus);
  hipLaunchKernelGGL(pool_partial, dim3(C_LEN / 64, B_LEN, K3_NS), dim3(256), 0,
                     stream, x, focus, pool2);
  hipLaunchKernelGGL(pool_reduce, dim3((B_LEN * C_LEN) / 256), dim3(256), 0,
                     stream, pool2, out);
}

// Round 12
// 135.208 us; speedup vs baseline: 1.3212x; 1.3212x over previous
//
#include <hip/hip_runtime.h>

#define B_LEN 32
#define C_LEN 512
#define L_LEN 4096
#define H_LEN 8
#define WIN 9

typedef __attribute__((ext_vector_type(8))) short short8v;  // 8 bf16 = 16B
typedef __attribute__((ext_vector_type(4))) float float4v;

// fp32 -> bf16 RNE
__device__ __forceinline__ short f2bf(float f) {
  unsigned u = __float_as_uint(f);
  unsigned r = (u + 0x7fffu + ((u >> 16) & 1u)) >> 16;
  return (short)r;
}

// ------------- Kernel 0: repack W [H][C][9] -> Wt bf16 [9][16][512] ----------
// h rows 8..15 are ZERO so MFMA A-rows 8-15 produce zeros.
__global__ __launch_bounds__(256) void repack_w_bf16(
    const float* __restrict__ W, short* __restrict__ Wt)
{
  const int i = blockIdx.x * 256 + threadIdx.x; // over 9*16*512
  if (i >= WIN * 16 * C_LEN) return;
  const int c = i & 511;
  const int h = (i >> 9) & 15;
  const int w = i / (16 * C_LEN);
  const float v = (h < H_LEN) ? W[((size_t)h * C_LEN + c) * WIN + w] : 0.f;
  Wt[i] = f2bf(v);
}

// ------------- Kernel 1: conv via bf16 MFMA, wave-autonomous pipeline --------
// grid (16 lt, 32 b) = 512 blocks (2/CU resident), block 256 (4 waves).
// Per chunk phase: WLOAD (9 W-frags FIRST -> deepest compute wait is
// vmcnt(9): the x prefetch stays in flight; the in-order-vmcnt drain that
// stalled R9/R10 once per chunk is gone) -> LOADK (next chunk's 9 x float4)
// -> COMPUTE (pure LDS+MFMA) -> WRITEB (drain x, cvt, swizzled ds_write).
// NO stagger (R11's regression): all waves walk chunks in the same order.
#define SLICE 5760 // 72 rows * 80 B

__global__ __launch_bounds__(256, 3) void conv_mfma(
    const float* __restrict__ x, const short* __restrict__ Wt,
    float* __restrict__ part)
{
  __shared__ short xt[4 * 2 * (SLICE / 2)]; // 46080 B
  const int t = threadIdx.x;
  const int lane = t & 63;
  const int wid = t >> 6;
  const int j15 = lane & 15;
  const int g = lane >> 4;
  const int g16 = g * 16;
  const int b = blockIdx.y;
  const int l0b = blockIdx.x * 256;
  const int wl0 = wid * 64;
  const int s = l0b + wl0 - 4; // slice row r <-> x[s + r]
  const float* xb = x + (size_t)b * C_LEN * L_LEN;

  char* bufA = (char*)&xt[0] + (size_t)wid * 2 * SLICE;
  char* bufB = bufA + SLICE;

  // staging lane roles
  const int q = lane & 15;      // l-quad (bulk rows 4+4q .. 7+4q)
  const int chigh = lane >> 4;  // c-octet 0..3
  const int bl = s + 4 + 4 * q; // bulk l (always in bounds)
  const int hside = lane >> 5;  // 0: rows 0-3, 1: rows 68-71
  const int hc = lane & 31;     // halo channel within chunk
  const int hl = s + (hside ? 68 : 0);
  const bool hok = (hl >= 0) && (hl + 3 < L_LEN);
  const int hlc = hok ? hl : (hside ? (L_LEN - 4) : 0); // safe clamped addr
  const int hr = hside ? 68 : 0;
  const int hkey = hside ? 16 : 0; // ((68>>2)&3)<<4 = 16; rows 0-3 -> 0

  float4 L0, L1, L2, L3, L4, L5, L6, L7, LH;
  short8v wn0, wn1, wn2, wn3, wn4, wn5, wn6, wn7, wn8;
  const float4 z4 = make_float4(0.f, 0.f, 0.f, 0.f);

#define WLOAD(K)                                                               \
  {                                                                            \
    const short* Wb = Wt + (K) * 32 + j15 * 512 + 8 * g;                       \
    wn0 = *(const short8v*)(Wb);                                               \
    wn1 = *(const short8v*)(Wb + 1 * 8192);                                    \
    wn2 = *(const short8v*)(Wb + 2 * 8192);                                    \
    wn3 = *(const short8v*)(Wb + 3 * 8192);                                    \
    wn4 = *(const short8v*)(Wb + 4 * 8192);                                    \
    wn5 = *(const short8v*)(Wb + 5 * 8192);                                    \
    wn6 = *(const short8v*)(Wb + 6 * 8192);                                    \
    wn7 = *(const short8v*)(Wb + 7 * 8192);                                    \
    wn8 = *(const short8v*)(Wb + 8 * 8192);                                    \
  }

#define LOADK(K)                                                               \
  {                                                                            \
    const float* bsrc = xb + (size_t)((K) * 32 + chigh * 8) * L_LEN + bl;      \
    L0 = *(const float4*)(bsrc);                                               \
    L1 = *(const float4*)(bsrc + 1 * (size_t)L_LEN);                           \
    L2 = *(const float4*)(bsrc + 2 * (size_t)L_LEN);                           \
    L3 = *(const float4*)(bsrc + 3 * (size_t)L_LEN);                           \
    L4 = *(const float4*)(bsrc + 4 * (size_t)L_LEN);                           \
    L5 = *(const float4*)(bsrc + 5 * (size_t)L_LEN);                           \
    L6 = *(const float4*)(bsrc + 6 * (size_t)L_LEN);                           \
    L7 = *(const float4*)(bsrc + 7 * (size_t)L_LEN);                           \
    LH = *(const float4*)(xb + (size_t)((K) * 32 + hc) * L_LEN + hlc);         \
    if (!hok) LH = z4;                                                         \
  }

#define WROW(BB, E, CMP)                                                       \
  {                                                                            \
    const int r = 4 + 4 * q + (E);                                             \
    short8v v = { f2bf(L0.CMP), f2bf(L1.CMP), f2bf(L2.CMP), f2bf(L3.CMP),      \
                  f2bf(L4.CMP), f2bf(L5.CMP), f2bf(L6.CMP), f2bf(L7.CMP) };    \
    *(short8v*)((BB) + r * 80 + ((chigh * 16) ^ (((r >> 2) & 3) << 4))) = v;   \
  }

#define WRITEB(BB)                                                             \
  {                                                                            \
    WROW(BB, 0, x) WROW(BB, 1, y) WROW(BB, 2, z) WROW(BB, 3, w)                \
    *(short*)((BB) + (hr + 0) * 80 + ((hc * 2) ^ hkey)) = f2bf(LH.x);          \
    *(short*)((BB) + (hr + 1) * 80 + ((hc * 2) ^ hkey)) = f2bf(LH.y);          \
    *(short*)((BB) + (hr + 2) * 80 + ((hc * 2) ^ hkey)) = f2bf(LH.z);          \
    *(short*)((BB) + (hr + 3) * 80 + ((hc * 2) ^ hkey)) = f2bf(LH.w);          \
  }

#define MSTEP(BB, ROFF, ACC, WF)                                               \
  {                                                                            \
    const int r = rw + (ROFF);                                                 \
    short8v xf = *(const short8v*)((BB) + r * 80 + (g16 ^ (((r >> 2) & 3) << 4))); \
    ACC = __builtin_amdgcn_mfma_f32_16x16x32_bf16(WF, xf, ACC, 0, 0, 0);       \
  }

#define CSTEP(BB, W, WF)                                                       \
  {                                                                            \
    const int rw = j15 + (W);                                                  \
    MSTEP(BB, 0, acc0, WF) MSTEP(BB, 16, acc1, WF)                             \
    MSTEP(BB, 32, acc2, WF) MSTEP(BB, 48, acc3, WF)                            \
  }

#define COMPUTE(BB)                                                            \
  {                                                                            \
    CSTEP(BB, 0, wn0) CSTEP(BB, 1, wn1) CSTEP(BB, 2, wn2)                      \
    CSTEP(BB, 3, wn3) CSTEP(BB, 4, wn4) CSTEP(BB, 5, wn5)                      \
    CSTEP(BB, 6, wn6) CSTEP(BB, 7, wn7) CSTEP(BB, 8, wn8)                      \
  }

  float4v acc0 = {0.f, 0.f, 0.f, 0.f};
  float4v acc1 = acc0, acc2 = acc0, acc3 = acc0;

  // NO stagger (single-variable change vs R11; R10 had st=wid*4 implicit 0 too)
#define CK(I) (I)

  // prologue: stage chunk 0 into bufA
  LOADK(CK(0))
  WRITEB(bufA)

  for (int i = 0; i < 16; i += 2) {
    // phase A: compute CK(i) from bufA; prefetch x of CK(i+1)
    WLOAD(CK(i))          // W first: compute waits vmcnt(9), x stays in flight
    LOADK(CK(i + 1))
    COMPUTE(bufA)
    WRITEB(bufB)
    // phase B: compute CK(i+1) from bufB; prefetch x of CK(i+2)
    WLOAD(CK(i + 1))
    if (i + 2 < 16) { LOADK(CK(i + 2)) }
    COMPUTE(bufB)
    if (i + 2 < 16) { WRITEB(bufA) }
  }

  // D: col = lane&15 = l-offset, row = (lane>>4)*4 + reg = h (valid g<2)
  if (lane < 32) {
    float* d = part + ((size_t)b * H_LEN + 4 * g) * L_LEN + (l0b + wl0 + j15);
#pragma unroll
    for (int r = 0; r < 4; ++r) {
      d[(size_t)r * L_LEN +  0] = acc0[r];
      d[(size_t)r * L_LEN + 16] = acc1[r];
      d[(size_t)r * L_LEN + 32] = acc2[r];
      d[(size_t)r * L_LEN + 48] = acc3[r];
    }
  }
#undef WLOAD
#undef LOADK
#undef WROW
#undef WRITEB
#undef MSTEP
#undef CSTEP
#undef COMPUTE
#undef CK
}

// ------------- Kernel 2: softmax over L --------------------------------------
__global__ __launch_bounds__(256) void softmax_rows(
    const float* __restrict__ part, float* __restrict__ focus)
{
  __shared__ float red[256];
  const int r = blockIdx.x; // b*H + h
  const int t = threadIdx.x;
  float v[16];
#pragma unroll
  for (int k = 0; k < 4; ++k) {
    const int i4 = (t + 256 * k) * 4;
    float4 a = *reinterpret_cast<const float4*>(&part[(size_t)r * L_LEN + i4]);
    v[4 * k + 0] = a.x; v[4 * k + 1] = a.y; v[4 * k + 2] = a.z; v[4 * k + 3] = a.w;
  }
  // bias b[h] is constant along L -> softmax-invariant -> skipped
  float m = v[0];
#pragma unroll
  for (int k = 1; k < 16; ++k) m = fmaxf(m, v[k]);
  red[t] = m;
  __syncthreads();
  for (int s = 128; s > 0; s >>= 1) {
    if (t < s) red[t] = fmaxf(red[t], red[t + s]);
    __syncthreads();
  }
  m = red[0];
  __syncthreads();
  float sum = 0.f;
#pragma unroll
  for (int k = 0; k < 16; ++k) { v[k] = __expf(v[k] - m); sum += v[k]; }
  red[t] = sum;
  __syncthreads();
  for (int s = 128; s > 0; s >>= 1) {
    if (t < s) red[t] += red[t + s];
    __syncthreads();
  }
  const float inv = 1.f / red[0];
#pragma unroll
  for (int k = 0; k < 4; ++k) {
    const int i4 = (t + 256 * k) * 4;
    float4 a;
    a.x = v[4 * k + 0] * inv; a.y = v[4 * k + 1] * inv;
    a.z = v[4 * k + 2] * inv; a.w = v[4 * k + 3] * inv;
    *reinterpret_cast<float4*>(&focus[(size_t)r * L_LEN + i4]) = a;
  }
}

// ------------- Kernel 3a: partial pooled over an L-split ---------------------
#define K3_ST 68
#define K3_NS 4

__global__ __launch_bounds__(256) void pool_partial(
    const float* __restrict__ x, const float* __restrict__ focus,
    float* __restrict__ pool2)
{
  __shared__ float xs[64 * K3_ST];
  const int t = threadIdx.x;
  const int cl = t & 63;
  const int p = t >> 6;
  const int pu = __builtin_amdgcn_readfirstlane(p);
  const int b = blockIdx.y;
  const int c0 = blockIdx.x * 64;
  const int lbeg = blockIdx.z * (L_LEN / K3_NS);
  const float* f0 = focus + ((size_t)b * H_LEN + pu) * L_LEN;
  const float* f1 = f0 + 4 * (size_t)L_LEN;
  const float* xb = x + (size_t)b * C_LEN * L_LEN;
  const int srow = t >> 4;
  const int scol = (t & 15) * 4;
  float acc0 = 0.f, acc1 = 0.f;

  for (int l0 = lbeg; l0 < lbeg + L_LEN / K3_NS; l0 += 64) {
    __syncthreads();
#pragma unroll
    for (int pass = 0; pass < 4; ++pass) {
      const int c = srow + pass * 16;
      float4 v = *reinterpret_cast<const float4*>(&xb[(size_t)(c0 + c) * L_LEN + l0 + scol]);
      *reinterpret_cast<float4*>(&xs[c * K3_ST + scol]) = v;
    }
    __syncthreads();
#pragma unroll
    for (int l4 = 0; l4 < 16; ++l4) {
      const float4 xv = *reinterpret_cast<const float4*>(&xs[cl * K3_ST + 4 * l4]);
      const int li = l0 + 4 * l4;
      acc0 = fmaf(xv.x, f0[li + 0], acc0);
      acc0 = fmaf(xv.y, f0[li + 1], acc0);
      acc0 = fmaf(xv.z, f0[li + 2], acc0);
      acc0 = fmaf(xv.w, f0[li + 3], acc0);
      acc1 = fmaf(xv.x, f1[li + 0], acc1);
      acc1 = fmaf(xv.y, f1[li + 1], acc1);
      acc1 = fmaf(xv.z, f1[li + 2], acc1);
      acc1 = fmaf(xv.w, f1[li + 3], acc1);
    }
  }
  float* dst = pool2 + (((size_t)blockIdx.z * B_LEN + b) * C_LEN + c0 + cl) * H_LEN;
  dst[p] = acc0;
  dst[p + 4] = acc1;
}

// ------------- Kernel 3b: sum L-splits, max over heads ------------------------
__global__ __launch_bounds__(256) void pool_reduce(
    const float* __restrict__ pool2, float* __restrict__ out)
{
  const int i = blockIdx.x * 256 + threadIdx.x; // over B*C
  float s[H_LEN];
#pragma unroll
  for (int h = 0; h < H_LEN; ++h) s[h] = 0.f;
  for (int ls = 0; ls < K3_NS; ++ls) {
    const float* src = pool2 + ((size_t)ls * B_LEN * C_LEN + i) * H_LEN;
    float4 a = *reinterpret_cast<const float4*>(src);
    float4 b4 = *reinterpret_cast<const float4*>(src + 4);
    s[0] += a.x; s[1] += a.y; s[2] += a.z; s[3] += a.w;
    s[4] += b4.x; s[5] += b4.y; s[6] += b4.z; s[7] += b4.w;
  }
  float m = s[0];
#pragma unroll
  for (int h = 1; h < H_LEN; ++h) m = fmaxf(m, s[h]);
  out[i] = m;
}

extern "C" void kernel_launch(void* const* d_in, const int* in_sizes, int n_in,
                              void* d_out, int out_size, void* d_ws, size_t ws_size,
                              hipStream_t stream)
{
  const float* x = (const float*)d_in[0];
  const float* W = (const float*)d_in[1];
  // d_in[2] = bias: constant along L, softmax-invariant -> no effect on output.
  float* out = (float*)d_out;
  float* ws = (float*)d_ws;

  const size_t PART = (size_t)B_LEN * H_LEN * L_LEN;            // 1M floats
  const size_t POOL2N = (size_t)K3_NS * B_LEN * C_LEN * H_LEN;  // 512K floats

  float* part = ws;                      // 4 MB
  float* focus = ws + PART;              // 4 MB
  float* pool2 = focus + PART;           // 2 MB
  short* Wt = (short*)(pool2 + POOL2N);  // 147 KB

  hipLaunchKernelGGL(repack_w_bf16, dim3((WIN * 16 * C_LEN + 255) / 256), dim3(256), 0,
                     stream, W, Wt);
  hipLaunchKernelGGL(conv_mfma, dim3(L_LEN / 256, B_LEN), dim3(256), 0,
                     stream, x, Wt, part);
  hipLaunchKernelGGL(softmax_rows, dim3(B_LEN * H_LEN), dim3(256), 0,
                     stream, part, focus);
  hipLaunchKernelGGL(pool_partial, dim3(C_LEN / 64, B_LEN, K3_NS), dim3(256), 0,
                     stream, x, focus, pool2);
  hipLaunchKernelGGL(pool_reduce, dim3((B_LEN * C_LEN) / 256), dim3(256), 0,
                     stream, pool2, out);
}